// Round 4
// baseline (131.409 us; speedup 1.0000x reference)
//
#include <hip/hip_runtime.h>
#include <hip/hip_bf16.h>

// UncompressTransformLayer: scatter compressed strict-upper-triangular vector
// (row-major triu order, k=1) into a dense [n,n] fp32 matrix, zeros elsewhere.
// n = 8192, m = n*(n-1)/2 = 33,550,336.
//
// Memory-bound: 256 MiB write (all of out, every call) + 128 MiB read.
// Floor ~ 402 MB / 6.3 TB/s ~ 64 us.
// R1: scalar reads, plain stores            -> 100 us (4.0 TB/s)
// R2: nt stores + 8-wide units              -> 116 us (regressed; reverted)
// R3: aligned f32x4-pair + funnel select    ->  93 us (4.3 TB/s)
// R4: single UNALIGNED dwordx4 read per quad (gfx950 global loads are
//     dword-granular), 64B output chunk per thread per iter, unroll.

#define N_DIM 8192
#define M_TOTAL 33550336u
#define UNITS_PER_ROW 512u                    // units of 16 floats (64B)
#define TOTAL_UNITS (8192u * UNITS_PER_ROW)   // 4,194,304
#define NTHREADS (2048u * 256u)               // 524,288 threads
#define ITERS (TOTAL_UNITS / NTHREADS)        // 8 per thread, exact

typedef float f32x4 __attribute__((ext_vector_type(4)));
// 4-byte-aligned 16B vector: lets clang emit global_load_dwordx4 at align 4
typedef float f32x4_u __attribute__((ext_vector_type(4), aligned(4)));

__global__ void __launch_bounds__(256)
uncompress_kernel(const float* __restrict__ comp, float* __restrict__ out) {
    const unsigned tid = blockIdx.x * blockDim.x + threadIdx.x;
#pragma unroll 2
    for (unsigned it = 0; it < ITERS; ++it) {
        const unsigned u  = tid + it * NTHREADS;
        const unsigned i  = u >> 9;           // row (u / 512)
        const unsigned j0 = (u & 511u) << 4;  // starting column (16-float unit)

        f32x4 q0, q1, q2, q3;
        if (j0 + 15u <= i) {
            // whole unit at/below diagonal -> zeros
            q0 = q1 = q2 = q3 = (f32x4)0.f;
        } else {
            // compressed index for (i, j), j > i:
            //   idx = Offset(i) + (j - i - 1),  Offset(i) = i*(n-1) - i*(i-1)/2
            //   base = Offset(i) - i - 1  (idx = base + j; u32 wrap benign)
            const unsigned off  = i * (N_DIM - 1) - ((i * (i - 1u)) >> 1);
            const unsigned base = off - i - 1u;
            if (j0 > i) {
                // fully above diagonal: 4 unaligned 16B loads, exactly the
                // 16 needed elements [c0, c0+15], no overread, coalesced
                // (contiguous 4KiB+ per wave).
                const unsigned c0 = base + j0;
                const f32x4_u* p = reinterpret_cast<const f32x4_u*>(comp + c0);
                q0 = p[0]; q1 = p[1]; q2 = p[2]; q3 = p[3];
            } else {
                // unit straddles the diagonal (1 per row): scalar predicated
                float t[16];
#pragma unroll
                for (int k = 0; k < 16; ++k)
                    t[k] = (j0 + (unsigned)k > i) ? comp[base + j0 + k] : 0.f;
                q0 = (f32x4){t[0], t[1], t[2], t[3]};
                q1 = (f32x4){t[4], t[5], t[6], t[7]};
                q2 = (f32x4){t[8], t[9], t[10], t[11]};
                q3 = (f32x4){t[12], t[13], t[14], t[15]};
            }
        }
        // 4 coalesced 16B stores (64B contiguous per thread, aligned)
        f32x4* o = reinterpret_cast<f32x4*>(out + ((size_t)i << 13) + j0);
        o[0] = q0; o[1] = q1; o[2] = q2; o[3] = q3;
    }
}

extern "C" void kernel_launch(void* const* d_in, const int* in_sizes, int n_in,
                              void* d_out, int out_size, void* d_ws, size_t ws_size,
                              hipStream_t stream) {
    const float* comp = (const float*)d_in[0];
    float* out = (float*)d_out;

    // 2048 blocks x 256 threads = 32 waves/CU; each thread does exactly
    // ITERS=8 units of 64B.
    const int block = 256;
    const int grid  = 2048;
    uncompress_kernel<<<grid, block, 0, stream>>>(comp, out);
}

// Round 5
// 100.464 us; speedup vs baseline: 1.3080x; 1.3080x over previous
//
#include <hip/hip_runtime.h>
#include <hip/hip_bf16.h>

// UncompressTransformLayer: scatter compressed strict-upper-triangular vector
// (row-major triu order, k=1) into a dense [n,n] fp32 matrix, zeros elsewhere.
// n = 8192, m = n*(n-1)/2 = 33,550,336.
//
// Memory-bound: 256 MiB write (all of out, every call) + 128 MiB read.
// Floor ~ 402 MB / 6.3 TB/s ~ 64 us.
// R1: scalar reads, plain stores            -> 100 us (4.0 TB/s)
// R2: nt stores + 8-wide units              -> 116 us (regressed; reverted)
// R3: aligned f32x4-pair + funnel select    ->  93 us (4.3 TB/s)
// R4: 64B/thread chunks + unaligned reads   -> 131 us (lane stride must be 16B!)
// R5: R3 skeleton, funnel replaced by ONE unaligned dwordx4 read per quad
//     (single change; lane stride stays 16B on both streams).

#define N_DIM 8192
#define M_TOTAL 33550336u
#define QUADS_PER_ROW (N_DIM / 4)            // 2048
#define TOTAL_QUADS (N_DIM * QUADS_PER_ROW)  // 16,777,216 (fits u32)

typedef float f32x4 __attribute__((ext_vector_type(4)));
// 4-byte-aligned 16B vector: clang emits global_load_dwordx4 with align 4
typedef float f32x4_u __attribute__((ext_vector_type(4), aligned(4)));

__global__ void __launch_bounds__(256)
uncompress_kernel(const float* __restrict__ comp, float* __restrict__ out) {
    const unsigned stride = gridDim.x * blockDim.x;
    for (unsigned q = blockIdx.x * blockDim.x + threadIdx.x;
         q < (unsigned)TOTAL_QUADS; q += stride) {
        const unsigned i  = q >> 11;          // row  (q / 2048)
        const unsigned j0 = (q & 2047u) << 2; // starting column of this quad

        f32x4 v4;
        if (j0 + 3u <= i) {
            // entire quad at/below diagonal -> zeros
            v4 = (f32x4)0.f;
        } else {
            // compressed index for (i, j), j > i:
            //   idx = Offset(i) + (j - i - 1),  Offset(i) = i*(n-1) - i*(i-1)/2
            //   base = Offset(i) - i - 1  (idx = base + j)
            const unsigned off  = i * (N_DIM - 1) - ((i * (i - 1u)) >> 1);
            const unsigned base = off - i - 1u;   // u32 wrap only for i=0,
                                                  // never used with j<=i
            if (j0 > i) {
                // fully above diagonal: ONE unaligned 16B load reading exactly
                // comp[c0..c0+3]. Last quad of row i ends exactly at the row's
                // last compressed element -> no overread. Wave-contiguous.
                const unsigned c0 = base + j0;
                v4 = *reinterpret_cast<const f32x4_u*>(comp + c0);
            } else {
                // straddles the diagonal (1 quad per row): scalar predicated
                v4.x = (j0 + 0u > i) ? comp[base + j0 + 0u] : 0.f;
                v4.y = (j0 + 1u > i) ? comp[base + j0 + 1u] : 0.f;
                v4.z = (j0 + 2u > i) ? comp[base + j0 + 2u] : 0.f;
                v4.w = (j0 + 3u > i) ? comp[base + j0 + 3u] : 0.f;
            }
        }
        // coalesced 16B store (normal, write-combines in L2)
        *reinterpret_cast<f32x4*>(out + ((size_t)i << 13) + j0) = v4;
    }
}

extern "C" void kernel_launch(void* const* d_in, const int* in_sizes, int n_in,
                              void* d_out, int out_size, void* d_ws, size_t ws_size,
                              hipStream_t stream) {
    const float* comp = (const float*)d_in[0];
    float* out = (float*)d_out;

    // 2048 blocks x 256 threads = 32 waves/CU (full); 32 quads per thread.
    const int block = 256;
    const int grid  = 2048;
    uncompress_kernel<<<grid, block, 0, stream>>>(comp, out);
}